// Round 2
// baseline (544.887 us; speedup 1.0000x reference)
//
#include <hip/hip_runtime.h>
#include <math.h>

#define BB 32
#define MM 2048
#define NN 1024           // 2*hid
#define C_SCALE 2.88539008177793f   // 2*log2(e): tanh(a) = 1 - 2/(2^(C*a)+1)
#define L2E 1.44269504088896f

#if __has_builtin(__builtin_amdgcn_exp2f)
#define EXP2F(x) __builtin_amdgcn_exp2f(x)
#else
#define EXP2F(x) exp2f(x)
#endif
#if __has_builtin(__builtin_amdgcn_rcpf)
#define RCPF(x) __builtin_amdgcn_rcpf(x)
#else
#define RCPF(x) (1.0f / (x))
#endif

__device__ __forceinline__ float waveReduceSum(float x) {
#pragma unroll
    for (int off = 32; off > 0; off >>= 1) x += __shfl_xor(x, off, 64);
    return x;
}
__device__ __forceinline__ float waveReduceMax(float x) {
#pragma unroll
    for (int off = 32; off > 0; off >>= 1) x = fmaxf(x, __shfl_xor(x, off, 64));
    return x;
}

// K1: dec_s[b*NN+n] = (h[b,:] . Wd[n,:] + bd[n]) * C_SCALE
// grid = NN blocks of 256. Block-wide coalesced Wd row load (4 KB).
__global__ __launch_bounds__(256) void k_dec(const float* __restrict__ h,
                                             const float* __restrict__ Wd,
                                             const float* __restrict__ bd,
                                             float* __restrict__ dec_s) {
    const int n = blockIdx.x;
    const int t = threadIdx.x;
    const int lane = t & 63, wave = t >> 6;
    const float4 wd4 = *(const float4*)(Wd + (size_t)n * NN + t * 4);
    __shared__ float red[BB][4];
#pragma unroll
    for (int b = 0; b < BB; ++b) {
        const float4 h4 = *(const float4*)(h + b * NN + t * 4);
        float p = wd4.x * h4.x + wd4.y * h4.y + wd4.z * h4.z + wd4.w * h4.w;
        p = waveReduceSum(p);
        if (lane == 0) red[b][wave] = p;
    }
    __syncthreads();
    if (t < BB) {
        float s = red[t][0] + red[t][1] + red[t][2] + red[t][3];
        dec_s[t * NN + n] = (s + bd[n]) * C_SCALE;
    }
}

// K2: scores[b,m] = sum_n tanh(ef[b,m,n] + dec[b,n] + cov[b,m]*wc[n]) * v[n]
// grid = BB*32 blocks of 256 (4 waves); each wave: 16 rows of one batch.
__global__ __launch_bounds__(256) void k_scores(const float* __restrict__ ef,
                                                const float* __restrict__ dec_s,
                                                const float* __restrict__ wc,
                                                const float* __restrict__ v,
                                                const float* __restrict__ cov,
                                                float* __restrict__ scores) {
    const int t = threadIdx.x;
    const int lane = t & 63, wave = t >> 6;
    const int b = blockIdx.x >> 5;
    const int mblk = blockIdx.x & 31;
    const int m0 = mblk * 64 + wave * 16;

    float4 dec4[4], wcs4[4], v4[4];
#pragma unroll
    for (int it = 0; it < 4; ++it) {
        const int k = it * 256 + lane * 4;
        dec4[it] = *(const float4*)(dec_s + b * NN + k);
        float4 w = *(const float4*)(wc + k);
        wcs4[it] = make_float4(w.x * C_SCALE, w.y * C_SCALE, w.z * C_SCALE, w.w * C_SCALE);
        v4[it] = *(const float4*)(v + k);
    }

    for (int mm = 0; mm < 16; ++mm) {
        const int m = m0 + mm;
        const float cv = cov[b * MM + m];
        const float* row = ef + (size_t)(b * MM + m) * NN;
        float acc = 0.f;
#pragma unroll
        for (int it = 0; it < 4; ++it) {
            const float4 e4 = *(const float4*)(row + it * 256 + lane * 4);
            {
                float x = fmaf(C_SCALE, e4.x, dec4[it].x); x = fmaf(cv, wcs4[it].x, x);
                float r = RCPF(EXP2F(x) + 1.0f);
                acc = fmaf(fmaf(-2.0f, r, 1.0f), v4[it].x, acc);
            }
            {
                float x = fmaf(C_SCALE, e4.y, dec4[it].y); x = fmaf(cv, wcs4[it].y, x);
                float r = RCPF(EXP2F(x) + 1.0f);
                acc = fmaf(fmaf(-2.0f, r, 1.0f), v4[it].y, acc);
            }
            {
                float x = fmaf(C_SCALE, e4.z, dec4[it].z); x = fmaf(cv, wcs4[it].z, x);
                float r = RCPF(EXP2F(x) + 1.0f);
                acc = fmaf(fmaf(-2.0f, r, 1.0f), v4[it].z, acc);
            }
            {
                float x = fmaf(C_SCALE, e4.w, dec4[it].w); x = fmaf(cv, wcs4[it].w, x);
                float r = RCPF(EXP2F(x) + 1.0f);
                acc = fmaf(fmaf(-2.0f, r, 1.0f), v4[it].w, acc);
            }
        }
        acc = waveReduceSum(acc);
        if (lane == 0) scores[b * MM + m] = acc;
    }
}

// K3: softmax over m, mask, renormalize, new_coverage. grid = BB blocks of 256.
// softmax denom cancels against renorm: out_i = e_i*keep_i / sum_j(e_j*keep_j)
__global__ __launch_bounds__(256) void k_softmax(const float* __restrict__ scores,
                                                 const float* __restrict__ mask,
                                                 const float* __restrict__ cov,
                                                 float* __restrict__ attn_out,
                                                 float* __restrict__ cov_out) {
    const int b = blockIdx.x;
    const int t = threadIdx.x;
    const int lane = t & 63, wave = t >> 6;
    __shared__ float red[4];

    float s[8];
    float mx = -3.0e38f;
#pragma unroll
    for (int i = 0; i < 8; ++i) {
        s[i] = scores[b * MM + i * 256 + t];
        mx = fmaxf(mx, s[i]);
    }
    mx = waveReduceMax(mx);
    if (lane == 0) red[wave] = mx;
    __syncthreads();
    mx = fmaxf(fmaxf(red[0], red[1]), fmaxf(red[2], red[3]));
    __syncthreads();

    float g[8];
    float ls = 0.f;
#pragma unroll
    for (int i = 0; i < 8; ++i) {
        float keep = 1.0f - mask[b * MM + i * 256 + t];
        g[i] = EXP2F((s[i] - mx) * L2E) * keep;
        ls += g[i];
    }
    ls = waveReduceSum(ls);
    if (lane == 0) red[wave] = ls;
    __syncthreads();
    const float S = red[0] + red[1] + red[2] + red[3];
    const float inv = RCPF(S);
#pragma unroll
    for (int i = 0; i < 8; ++i) {
        const int idx = b * MM + i * 256 + t;
        const float a = g[i] * inv;
        attn_out[idx] = a;
        cov_out[idx] = cov[idx] + a;
    }
}

// K4: partial context. grid = BB*64 blocks of 256; block = (b, 32-row m-chunk) x all N.
__global__ __launch_bounds__(256) void k_ctx_partial(const float* __restrict__ eo,
                                                     const float* __restrict__ attn,
                                                     float* __restrict__ part) {
    const int b = blockIdx.x >> 6;
    const int p = blockIdx.x & 63;
    const int t = threadIdx.x;
    const int n = t * 4;
    const float* base = eo + ((size_t)b * MM + p * 32) * NN + n;
    float4 acc = make_float4(0.f, 0.f, 0.f, 0.f);
#pragma unroll 4
    for (int mm = 0; mm < 32; ++mm) {
        const float a = attn[b * MM + p * 32 + mm];
        const float4 e = *(const float4*)(base + (size_t)mm * NN);
        acc.x = fmaf(a, e.x, acc.x);
        acc.y = fmaf(a, e.y, acc.y);
        acc.z = fmaf(a, e.z, acc.z);
        acc.w = fmaf(a, e.w, acc.w);
    }
    *(float4*)(part + ((size_t)(b * 64 + p)) * NN + n) = acc;
}

// K5: reduce 64 partials. grid = BB*NN/256 blocks of 256.
__global__ __launch_bounds__(256) void k_ctx_reduce(const float* __restrict__ part,
                                                    float* __restrict__ ctx) {
    const int idx = blockIdx.x * 256 + threadIdx.x;  // over BB*NN
    const int b = idx >> 10;
    const int n = idx & 1023;
    float s = 0.f;
#pragma unroll 8
    for (int p = 0; p < 64; ++p) s += part[((size_t)(b * 64 + p)) * NN + n];
    ctx[idx] = s;
}

extern "C" void kernel_launch(void* const* d_in, const int* in_sizes, int n_in,
                              void* d_out, int out_size, void* d_ws, size_t ws_size,
                              hipStream_t stream) {
    const float* h    = (const float*)d_in[0];   // [B, N]
    const float* eo   = (const float*)d_in[1];   // [B, M, N]
    const float* ef   = (const float*)d_in[2];   // [B*M, N]
    const float* mask = (const float*)d_in[3];   // [B, M]
    const float* cov  = (const float*)d_in[4];   // [B, M]
    const float* Wd   = (const float*)d_in[5];   // [N, N]
    const float* bd   = (const float*)d_in[6];   // [N]
    const float* wc   = (const float*)d_in[7];   // [N]
    const float* v    = (const float*)d_in[8];   // [N]

    float* out  = (float*)d_out;
    float* ctx  = out;                 // [B, N]
    float* attn = out + BB * NN;       // [B, M]
    float* ncov = attn + BB * MM;      // [B, M]

    float* dec_s  = (float*)d_ws;            // B*N floats
    float* scores = dec_s + BB * NN;         // B*M floats
    float* part   = scores + BB * MM;        // B*64*N floats (8 MB)

    k_dec<<<NN, 256, 0, stream>>>(h, Wd, bd, dec_s);
    k_scores<<<BB * 32, 256, 0, stream>>>(ef, dec_s, wc, v, cov, scores);
    k_softmax<<<BB, 256, 0, stream>>>(scores, mask, cov, attn, ncov);
    k_ctx_partial<<<BB * 64, 256, 0, stream>>>(eo, attn, part);
    k_ctx_reduce<<<(BB * NN) / 256, 256, 0, stream>>>(part, ctx);
}